// Round 1
// baseline (458.284 us; speedup 1.0000x reference)
//
#include <hip/hip_runtime.h>
#include <hip/hip_bf16.h>

#define NUM_PROCS 16
#define PROC_DIM 8
#define SPATIAL_DIM 3
#define ROW_DIM (PROC_DIM + SPATIAL_DIM)   // 11
#define ROWS_PER_BLOCK 256
#define BLOCK 256

__global__ __launch_bounds__(BLOCK) void gather_concat_kernel(
    const float* __restrict__ proc_pos,   // [16, 8]
    const float* __restrict__ locs_sp,    // [500000, 3]
    const int*   __restrict__ process_ids,// [NAUG]
    const int*   __restrict__ location_ids,// [NAUG]
    float* __restrict__ out,              // [NAUG, 11]
    int naug)
{
    __shared__ float s[ROWS_PER_BLOCK * ROW_DIM];   // 256*11*4 = 11264 B

    const int t = threadIdx.x;
    const int block_row0 = blockIdx.x * ROWS_PER_BLOCK;
    const int row = block_row0 + t;

    if (row < naug) {
        const int p = process_ids[row];
        const int l = location_ids[row];

        // proc part: 8 contiguous floats, 32B-aligned (p*8 floats)
        const float4* pp = (const float4*)(proc_pos + (size_t)p * PROC_DIM);
        float4 p0 = pp[0];
        float4 p1 = pp[1];

        const float* lp = locs_sp + (size_t)l * SPATIAL_DIM;
        float l0 = lp[0];
        float l1 = lp[1];
        float l2 = lp[2];

        // stride-11 LDS writes: gcd(11,32)=1 -> conflict-free across the wave
        float* dst = s + t * ROW_DIM;
        dst[0] = p0.x; dst[1] = p0.y; dst[2] = p0.z; dst[3] = p0.w;
        dst[4] = p1.x; dst[5] = p1.y; dst[6] = p1.z; dst[7] = p1.w;
        dst[8] = l0;   dst[9] = l1;   dst[10] = l2;
    }
    __syncthreads();

    // Stream the block's 256*11 = 2816 floats (= 704 float4) to global,
    // fully coalesced. Base byte offset = blockIdx*11264, 16B-aligned.
    const int nrows = min(ROWS_PER_BLOCK, naug - block_row0);
    const int total_f = nrows * ROW_DIM;
    float4* out4 = (float4*)(out + (size_t)block_row0 * ROW_DIM);
    const float4* s4 = (const float4*)s;

    if (total_f == ROWS_PER_BLOCK * ROW_DIM) {
        // full block: 704 float4, 256 threads -> iterations 0..2 + tail 192
        #pragma unroll
        for (int i = t; i < (ROWS_PER_BLOCK * ROW_DIM) / 4; i += BLOCK) {
            out4[i] = s4[i];
        }
    } else {
        // tail block (not hit for NAUG=8M, kept for generality)
        float* outf = out + (size_t)block_row0 * ROW_DIM;
        for (int i = t; i < total_f; i += BLOCK) {
            outf[i] = s[i];
        }
    }
}

extern "C" void kernel_launch(void* const* d_in, const int* in_sizes, int n_in,
                              void* d_out, int out_size, void* d_ws, size_t ws_size,
                              hipStream_t stream) {
    const float* proc_pos     = (const float*)d_in[0];
    const float* locs_sp      = (const float*)d_in[1];
    const int*   process_ids  = (const int*)d_in[2];
    const int*   location_ids = (const int*)d_in[3];
    float* out = (float*)d_out;

    const int naug = in_sizes[2];   // 8,000,000
    const int grid = (naug + ROWS_PER_BLOCK - 1) / ROWS_PER_BLOCK;

    gather_concat_kernel<<<grid, BLOCK, 0, stream>>>(
        proc_pos, locs_sp, process_ids, location_ids, out, naug);
}

// Round 3
// 450.816 us; speedup vs baseline: 1.0166x; 1.0166x over previous
//
#include <hip/hip_runtime.h>
#include <hip/hip_bf16.h>

#define NUM_PROCS 16
#define PROC_DIM 8
#define SPATIAL_DIM 3
#define ROW_DIM (PROC_DIM + SPATIAL_DIM)   // 11
#define BLOCK 256
#define RPT 2                               // rows per thread
#define ROWS_PER_BLOCK (BLOCK * RPT)        // 512; 8,000,000 / 512 = 15625 exactly

// clang native vector type: accepted by __builtin_nontemporal_{load,store}
typedef float v4f __attribute__((ext_vector_type(4)));

__global__ __launch_bounds__(BLOCK) void gather_concat_kernel(
    const float* __restrict__ proc_pos,     // [16, 8]
    const float* __restrict__ locs_sp,      // [500000, 3]
    const int*   __restrict__ process_ids,  // [NAUG]
    const int*   __restrict__ location_ids, // [NAUG]
    float* __restrict__ out,                // [NAUG, 11]
    int naug)
{
    __shared__ float s[ROWS_PER_BLOCK * ROW_DIM];   // 512*11*4 = 22528 B -> 7 blocks/CU

    const int t = threadIdx.x;
    const int block_row0 = blockIdx.x * ROWS_PER_BLOCK;

    // Each thread handles rows (t) and (t + BLOCK) within the block's 512-row
    // window. Stride-BLOCK interleave keeps the LDS write stride at 11 words
    // (gcd(11,32)=1 -> conflict-free) while giving 2 independent gather chains
    // per thread for latency hiding.
    int   pid[RPT];
    int   lid[RPT];
    bool  valid[RPT];

    #pragma unroll
    for (int j = 0; j < RPT; ++j) {
        const int row = block_row0 + t + j * BLOCK;
        valid[j] = (row < naug);
        if (valid[j]) {
            pid[j] = __builtin_nontemporal_load(process_ids + row);
            lid[j] = __builtin_nontemporal_load(location_ids + row);
        }
    }

    #pragma unroll
    for (int j = 0; j < RPT; ++j) {
        if (!valid[j]) continue;
        // proc part: 8 contiguous floats, 32B-aligned; tiny table, L1-hot
        const v4f* pp = (const v4f*)(proc_pos + (size_t)pid[j] * PROC_DIM);
        v4f p0 = pp[0];
        v4f p1 = pp[1];
        // loc part: 3 scalar dwords (12B rows, only 4B-aligned)
        const float* lp = locs_sp + (size_t)lid[j] * SPATIAL_DIM;
        float l0 = lp[0];
        float l1 = lp[1];
        float l2 = lp[2];

        float* dst = s + (t + j * BLOCK) * ROW_DIM;   // stride 11 words across lanes
        dst[0] = p0.x; dst[1] = p0.y; dst[2] = p0.z; dst[3] = p0.w;
        dst[4] = p1.x; dst[5] = p1.y; dst[6] = p1.z; dst[7] = p1.w;
        dst[8] = l0;   dst[9] = l1;   dst[10] = l2;
    }
    __syncthreads();

    // Stream 512*11 = 5632 floats = 1408 v4f to global, fully coalesced.
    // Base byte offset = blockIdx * 22528 (16B-aligned). Non-temporal: output
    // is write-once, keep L2 for the locs_sp gather table.
    const int nrows   = min(ROWS_PER_BLOCK, naug - block_row0);
    const int total_f = nrows * ROW_DIM;
    const v4f* s4 = (const v4f*)s;

    if (total_f == ROWS_PER_BLOCK * ROW_DIM) {
        v4f* out4 = (v4f*)(out + (size_t)block_row0 * ROW_DIM);
        #pragma unroll
        for (int k = 0; k < (ROWS_PER_BLOCK * ROW_DIM) / 4 / BLOCK; ++k) {
            const int i = t + k * BLOCK;
            __builtin_nontemporal_store(s4[i], out4 + i);
        }
        // tail: 1408 = 5*256 + 128 -> lanes 0..127 store one more
        const int i = t + ((ROWS_PER_BLOCK * ROW_DIM) / 4 / BLOCK) * BLOCK;
        if (i < (ROWS_PER_BLOCK * ROW_DIM) / 4) {
            __builtin_nontemporal_store(s4[i], out4 + i);
        }
    } else {
        // generic tail block (not hit for NAUG=8M)
        float* outf = out + (size_t)block_row0 * ROW_DIM;
        for (int i = t; i < total_f; i += BLOCK) {
            outf[i] = s[i];
        }
    }
}

extern "C" void kernel_launch(void* const* d_in, const int* in_sizes, int n_in,
                              void* d_out, int out_size, void* d_ws, size_t ws_size,
                              hipStream_t stream) {
    const float* proc_pos     = (const float*)d_in[0];
    const float* locs_sp      = (const float*)d_in[1];
    const int*   process_ids  = (const int*)d_in[2];
    const int*   location_ids = (const int*)d_in[3];
    float* out = (float*)d_out;

    const int naug = in_sizes[2];   // 8,000,000
    const int grid = (naug + ROWS_PER_BLOCK - 1) / ROWS_PER_BLOCK;

    gather_concat_kernel<<<grid, BLOCK, 0, stream>>>(
        proc_pos, locs_sp, process_ids, location_ids, out, naug);
}

// Round 4
// 449.785 us; speedup vs baseline: 1.0189x; 1.0023x over previous
//
#include <hip/hip_runtime.h>
#include <hip/hip_bf16.h>

#define NUM_PROCS 16
#define PROC_DIM 8
#define SPATIAL_DIM 3
#define ROW_DIM (PROC_DIM + SPATIAL_DIM)   // 11
#define BLOCK 256
#define RPT 2                               // rows per thread (consecutive pair)
#define ROWS_PER_BLOCK (BLOCK * RPT)        // 512; 8,000,000 / 512 = 15625 exactly

// clang native vector types: accepted by __builtin_nontemporal_{load,store}
typedef float v4f __attribute__((ext_vector_type(4)));
typedef int   v2i __attribute__((ext_vector_type(2)));

__global__ __launch_bounds__(BLOCK) void gather_concat_kernel(
    const float* __restrict__ proc_pos,     // [16, 8]
    const float* __restrict__ locs_sp,      // [500000, 3]
    const int*   __restrict__ process_ids,  // [NAUG]
    const int*   __restrict__ location_ids, // [NAUG]
    float* __restrict__ out,                // [NAUG, 11]
    int naug)
{
    __shared__ float sproc[NUM_PROCS * PROC_DIM];   // 512 B, staged once per block
    __shared__ float s[ROWS_PER_BLOCK * ROW_DIM];   // 22528 B -> 7 blocks/CU

    const int t = threadIdx.x;
    const int block_row0 = blockIdx.x * ROWS_PER_BLOCK;
    const bool full = (block_row0 + ROWS_PER_BLOCK <= naug);

    // Stage the whole proc table into LDS (128 dwords, threads 0..127).
    if (t < NUM_PROCS * PROC_DIM) sproc[t] = proc_pos[t];

    // Vectorized index loads: thread t owns rows 2t, 2t+1 of the block window.
    // int2 = 8 B/lane, 512 B/wave contiguous, NT (streamed once).
    const int r0 = block_row0 + 2 * t;
    v2i pid2, lid2;
    if (full) {
        pid2 = __builtin_nontemporal_load((const v2i*)(process_ids + block_row0) + t);
        lid2 = __builtin_nontemporal_load((const v2i*)(location_ids + block_row0) + t);
    } else {
        pid2.x = (r0     < naug) ? process_ids[r0]     : 0;
        pid2.y = (r0 + 1 < naug) ? process_ids[r0 + 1] : 0;
        lid2.x = (r0     < naug) ? location_ids[r0]     : 0;
        lid2.y = (r0 + 1 < naug) ? location_ids[r0 + 1] : 0;
    }

    // Issue the scattered locs gathers (the only compulsory global gathers)
    // BEFORE the staging barrier so their latency overlaps it.
    const float* lp0 = locs_sp + (size_t)lid2.x * SPATIAL_DIM;
    const float* lp1 = locs_sp + (size_t)lid2.y * SPATIAL_DIM;
    float a0 = lp0[0], a1 = lp0[1], a2 = lp0[2];
    float b0 = lp1[0], b1 = lp1[1], b2 = lp1[2];

    __syncthreads();   // sproc ready

    // Proc fragments from LDS: pid*32 B base, ds_read_b128 x2.
    // 16 distinct pids x 4 banks = avg 2-way aliasing -> free (m136).
    const v4f* pp0 = (const v4f*)(sproc + pid2.x * PROC_DIM);
    const v4f* pp1 = (const v4f*)(sproc + pid2.y * PROC_DIM);
    v4f p00 = pp0[0], p01 = pp0[1];
    v4f p10 = pp1[0], p11 = pp1[1];

    // Row writes at stride 22 words across lanes: 4-way bank aliasing (1.58x),
    // acceptable for 22 dword-writes/thread.
    float* d0 = s + (size_t)(2 * t) * ROW_DIM;
    d0[0] = p00.x; d0[1] = p00.y; d0[2] = p00.z; d0[3] = p00.w;
    d0[4] = p01.x; d0[5] = p01.y; d0[6] = p01.z; d0[7] = p01.w;
    d0[8] = a0;    d0[9] = a1;    d0[10] = a2;
    float* d1 = d0 + ROW_DIM;
    d1[0] = p10.x; d1[1] = p10.y; d1[2] = p10.z; d1[3] = p10.w;
    d1[4] = p11.x; d1[5] = p11.y; d1[6] = p11.z; d1[7] = p11.w;
    d1[8] = b0;    d1[9] = b1;    d1[10] = b2;

    __syncthreads();

    // Stream 512*11 = 5632 floats = 1408 v4f to global, fully coalesced.
    // Base byte offset = blockIdx * 22528 (16B-aligned). Non-temporal:
    // output is write-once; keep L2/L3 for the locs_sp gather table.
    const v4f* s4 = (const v4f*)s;
    if (full) {
        v4f* out4 = (v4f*)(out + (size_t)block_row0 * ROW_DIM);
        #pragma unroll
        for (int k = 0; k < (ROWS_PER_BLOCK * ROW_DIM) / 4 / BLOCK; ++k) {   // 5
            const int i = t + k * BLOCK;
            __builtin_nontemporal_store(s4[i], out4 + i);
        }
        const int i = t + ((ROWS_PER_BLOCK * ROW_DIM) / 4 / BLOCK) * BLOCK;
        if (i < (ROWS_PER_BLOCK * ROW_DIM) / 4) {                             // 128 lanes
            __builtin_nontemporal_store(s4[i], out4 + i);
        }
    } else {
        // generic tail block (not hit for NAUG=8M)
        const int total_f = (naug - block_row0) * ROW_DIM;
        float* outf = out + (size_t)block_row0 * ROW_DIM;
        for (int i = t; i < total_f; i += BLOCK) {
            outf[i] = s[i];
        }
    }
}

extern "C" void kernel_launch(void* const* d_in, const int* in_sizes, int n_in,
                              void* d_out, int out_size, void* d_ws, size_t ws_size,
                              hipStream_t stream) {
    const float* proc_pos     = (const float*)d_in[0];
    const float* locs_sp      = (const float*)d_in[1];
    const int*   process_ids  = (const int*)d_in[2];
    const int*   location_ids = (const int*)d_in[3];
    float* out = (float*)d_out;

    const int naug = in_sizes[2];   // 8,000,000
    const int grid = (naug + ROWS_PER_BLOCK - 1) / ROWS_PER_BLOCK;

    gather_concat_kernel<<<grid, BLOCK, 0, stream>>>(
        proc_pos, locs_sp, process_ids, location_ids, out, naug);
}